// Round 3
// baseline (466.811 us; speedup 1.0000x reference)
//
#include <hip/hip_runtime.h>
#include <stdint.h>

#define BB 16
#define LC 2048
#define LQ 1024
#define DD 512

typedef _Float16 f16x8 __attribute__((ext_vector_type(8)));
typedef _Float16 f16x4 __attribute__((ext_vector_type(4)));
typedef float f32x4 __attribute__((ext_vector_type(4)));

#define MFMA16 __builtin_amdgcn_mfma_f32_16x16x32_f16

// Async global->LDS, 16B per lane. LDS dest = wave-uniform base + lane*16.
__device__ __forceinline__ void async16(_Float16* lds, const _Float16* g) {
    __builtin_amdgcn_global_load_lds(
        (const __attribute__((address_space(1))) void*)g,
        (__attribute__((address_space(3))) void*)lds, 16, 0, 0);
}

// Zero H (fp32, vectorized) + lsum/cs stats region.
__global__ __launch_bounds__(256) void zero_k(float* __restrict__ H, float* __restrict__ stats) {
    const int i = blockIdx.x * 256 + threadIdx.x;
    if (i < (BB * LQ * DD) / 4) ((float4*)H)[i] = make_float4(0.f, 0.f, 0.f, 0.f);
    if (i < BB * LQ + BB * LC) stats[i] = 0.0f;
}

// One block per (b, 64 context rows), loops over all 8 d-chunks of 64.
// Writes cm = ctx*wm fp16, ct = ctx^T fp16, cb = ctx.wc directly (no atomics).
__global__ __launch_bounds__(256) void prep_ctx(
    const float* __restrict__ ctx, const float* __restrict__ w,
    _Float16* __restrict__ cm, _Float16* __restrict__ ct, float* __restrict__ cb)
{
    __shared__ _Float16 sm[64][68];
    const int b = blockIdx.y;
    const int i0 = blockIdx.x * 64;
    const int t = threadIdx.x;
    const int tx = t & 15, ty = t >> 4;
    float cbacc[4] = {0.f, 0.f, 0.f, 0.f};
    for (int dc = 0; dc < 8; ++dc) {
        const int d0 = dc * 64;
        const float4 wc4 = *(const float4*)(w + d0 + tx * 4);
        const float4 wm4 = *(const float4*)(w + 2 * DD + d0 + tx * 4);
        if (dc) __syncthreads();   // guard sm reuse
        for (int k = 0; k < 4; ++k) {
            const int r = ty + 16 * k;
            const int ig = i0 + r;
            const float4 v = *(const float4*)(ctx + ((size_t)(b * LC + ig)) * DD + d0 + tx * 4);
            f16x4 cmv = { (_Float16)(v.x * wm4.x), (_Float16)(v.y * wm4.y),
                          (_Float16)(v.z * wm4.z), (_Float16)(v.w * wm4.w) };
            *(f16x4*)(cm + ((size_t)(b * LC + ig)) * DD + d0 + tx * 4) = cmv;
            sm[tx * 4 + 0][r] = (_Float16)v.x;
            sm[tx * 4 + 1][r] = (_Float16)v.y;
            sm[tx * 4 + 2][r] = (_Float16)v.z;
            sm[tx * 4 + 3][r] = (_Float16)v.w;
            cbacc[k] += v.x * wc4.x + v.y * wc4.y + v.z * wc4.z + v.w * wc4.w;
        }
        __syncthreads();
        for (int k = 0; k < 4; ++k) {
            const int dd = ty + 16 * k;
            f16x4 o = *(const f16x4*)(&sm[dd][tx * 4]);
            *(f16x4*)(ct + ((size_t)(b * DD + d0 + dd)) * LC + i0 + tx * 4) = o;
        }
    }
    #pragma unroll
    for (int k = 0; k < 4; ++k) {
        float p = cbacc[k];
        p += __shfl_xor(p, 1); p += __shfl_xor(p, 2);
        p += __shfl_xor(p, 4); p += __shfl_xor(p, 8);
        if (tx == 0) cb[b * LC + i0 + ty + 16 * k] = p;
    }
}

// Per query row: fp16 copy, qb = q.wq, qmask = (sum(q) != 0)
__global__ __launch_bounds__(128) void prep_q(
    const float* __restrict__ q, const float* __restrict__ w,
    _Float16* __restrict__ qh, float* __restrict__ qb, float* __restrict__ qmask)
{
    const int j = blockIdx.x;
    const int t = threadIdx.x;
    const float* wq = w + DD;
    const float4 v = *(const float4*)(q + (size_t)j * DD + t * 4);
    const float4 wq4 = *(const float4*)(wq + t * 4);
    f16x4 qv = { (_Float16)v.x, (_Float16)v.y, (_Float16)v.z, (_Float16)v.w };
    *(f16x4*)(qh + (size_t)j * DD + t * 4) = qv;
    float dq = v.x * wq4.x + v.y * wq4.y + v.z * wq4.z + v.w * wq4.w;
    float sq = v.x + v.y + v.z + v.w;
    for (int m = 1; m < 64; m <<= 1) { dq += __shfl_xor(dq, m); sq += __shfl_xor(sq, m); }
    __shared__ float sd[2], ss[2];
    if ((t & 63) == 0) { sd[t >> 6] = dq; ss[t >> 6] = sq; }
    __syncthreads();
    if (t == 0) {
        qb[j] = sd[0] + sd[1];
        float s = ss[0] + ss[1];
        qmask[j] = (s != 0.0f) ? 1.0f : 0.0f;
    }
}

// GEMM1: E[b,j,i] = exp( qh[j,:].cm[b,i,:] + cb[b,i] + qb[j] ), fp16 out; lsum atomics.
// 128x128 block, BK=32, DOUBLE-BUFFERED async staging, ONE barrier per iter:
//   barrier (tile p ready) -> issue async loads for tile p^1 -> compute tile p.
__global__ __launch_bounds__(256) void gemm1(
    const _Float16* __restrict__ qh, const _Float16* __restrict__ cm,
    const float* __restrict__ cb, const float* __restrict__ qb,
    _Float16* __restrict__ E, float* __restrict__ lsum)
{
    __shared__ __align__(16) _Float16 smA[2][128 * 32];
    __shared__ __align__(16) _Float16 smB[2][128 * 32];
    const int b = blockIdx.z;
    const int m0 = blockIdx.x * 128;   // j
    const int n0 = blockIdx.y * 128;   // i
    const int t = threadIdx.x;
    const int lane = t & 63;
    const int wid = t >> 6;
    const int wvm = wid >> 1, wvn = wid & 1;
    const int li = lane & 15, lg = lane >> 4;
    f32x4 acc[4][4] = {};
    const int srow = lane >> 2;
    const int scol = (lane & 3) * 8;
    const int soff = wid * 32 * 32;    // wave's 32-row slab
    const _Float16* gA0 = qh + (size_t)(m0 + wid * 32 + srow) * DD + scol;
    const _Float16* gA1 = gA0 + (size_t)16 * DD;
    const _Float16* gB0 = cm + ((size_t)(b * LC + n0 + wid * 32 + srow)) * DD + scol;
    const _Float16* gB1 = gB0 + (size_t)16 * DD;
    // prologue: stage tile 0 into buffer 0
    async16(&smA[0][soff], gA0);
    async16(&smA[0][soff + 512], gA1);
    async16(&smB[0][soff], gB0);
    async16(&smB[0][soff + 512], gB1);
    #pragma unroll
    for (int it = 0; it < 16; ++it) {
        const int p = it & 1;
        __syncthreads();               // tile p staged & prev reads of p^1 done
        if (it + 1 < 16) {
            const int ks = (it + 1) * 32;
            async16(&smA[p ^ 1][soff], gA0 + ks);
            async16(&smA[p ^ 1][soff + 512], gA1 + ks);
            async16(&smB[p ^ 1][soff], gB0 + ks);
            async16(&smB[p ^ 1][soff + 512], gB1 + ks);
        }
        f16x8 af[4], bf[4];
        #pragma unroll
        for (int mt = 0; mt < 4; ++mt)
            af[mt] = *(const f16x8*)(&smA[p][(wvm * 64 + mt * 16 + li) * 32 + lg * 8]);
        #pragma unroll
        for (int nt = 0; nt < 4; ++nt)
            bf[nt] = *(const f16x8*)(&smB[p][(wvn * 64 + nt * 16 + li) * 32 + lg * 8]);
        #pragma unroll
        for (int mt = 0; mt < 4; ++mt)
            #pragma unroll
            for (int nt = 0; nt < 4; ++nt)
                acc[mt][nt] = MFMA16(af[mt], bf[nt], acc[mt][nt], 0, 0, 0);
    }
    __syncthreads();
    float* rs = (float*)smA;
    if (t < 128) rs[t] = 0.0f;
    __syncthreads();
    float cbv[4];
    #pragma unroll
    for (int nt = 0; nt < 4; ++nt) cbv[nt] = cb[b * LC + n0 + wvn * 64 + nt * 16 + li];
    #pragma unroll
    for (int mt = 0; mt < 4; ++mt) {
        #pragma unroll
        for (int r = 0; r < 4; ++r) {
            const int jl = wvm * 64 + mt * 16 + lg * 4 + r;
            const int j = m0 + jl;
            const float qbv = qb[j];
            _Float16* Erow = E + ((size_t)(b * LQ + j)) * LC + n0 + wvn * 64;
            float rsv = 0.0f;
            #pragma unroll
            for (int nt = 0; nt < 4; ++nt) {
                float e = __expf(acc[mt][nt][r] + cbv[nt] + qbv);
                rsv += e;
                Erow[nt * 16 + li] = (_Float16)e;
            }
            rsv += __shfl_xor(rsv, 1); rsv += __shfl_xor(rsv, 2);
            rsv += __shfl_xor(rsv, 4); rsv += __shfl_xor(rsv, 8);
            if (li == 0) atomicAdd(&rs[jl], rsv);
        }
    }
    __syncthreads();
    if (t < 128) atomicAdd(&lsum[b * LQ + m0 + t], rs[t]);
}

// GEMM2 (split-K x4): H[b,j,d] += (qmask[j]/lsum[b,j]) * sum_{i in chunk} E[b,j,i]*ct[b,d,i]
// Same double-buffered staging; KC = 512 per chunk; fp32 atomicAdd into zeroed H.
__global__ __launch_bounds__(256) void gemm2(
    const _Float16* __restrict__ E, const _Float16* __restrict__ ct,
    const float* __restrict__ lsum, const float* __restrict__ qmask,
    float* __restrict__ H)
{
    __shared__ __align__(16) _Float16 smA[2][128 * 32];
    __shared__ __align__(16) _Float16 smB[2][128 * 32];
    const int kc = blockIdx.z & 3;
    const int b  = blockIdx.z >> 2;
    const int m0 = blockIdx.x * 128;   // j
    const int n0 = blockIdx.y * 128;   // d
    const int t = threadIdx.x;
    const int lane = t & 63;
    const int wid = t >> 6;
    const int wvm = wid >> 1, wvn = wid & 1;
    const int li = lane & 15, lg = lane >> 4;
    f32x4 acc[4][4] = {};
    const int srow = lane >> 2;
    const int scol = (lane & 3) * 8;
    const int soff = wid * 32 * 32;
    const _Float16* gA0 = E + ((size_t)(b * LQ + m0 + wid * 32 + srow)) * LC + kc * 512 + scol;
    const _Float16* gA1 = gA0 + (size_t)16 * LC;
    const _Float16* gB0 = ct + ((size_t)(b * DD + n0 + wid * 32 + srow)) * LC + kc * 512 + scol;
    const _Float16* gB1 = gB0 + (size_t)16 * LC;
    async16(&smA[0][soff], gA0);
    async16(&smA[0][soff + 512], gA1);
    async16(&smB[0][soff], gB0);
    async16(&smB[0][soff + 512], gB1);
    #pragma unroll
    for (int it = 0; it < 16; ++it) {
        const int p = it & 1;
        __syncthreads();
        if (it + 1 < 16) {
            const int ks = (it + 1) * 32;
            async16(&smA[p ^ 1][soff], gA0 + ks);
            async16(&smA[p ^ 1][soff + 512], gA1 + ks);
            async16(&smB[p ^ 1][soff], gB0 + ks);
            async16(&smB[p ^ 1][soff + 512], gB1 + ks);
        }
        f16x8 af[4], bf[4];
        #pragma unroll
        for (int mt = 0; mt < 4; ++mt)
            af[mt] = *(const f16x8*)(&smA[p][(wvm * 64 + mt * 16 + li) * 32 + lg * 8]);
        #pragma unroll
        for (int nt = 0; nt < 4; ++nt)
            bf[nt] = *(const f16x8*)(&smB[p][(wvn * 64 + nt * 16 + li) * 32 + lg * 8]);
        #pragma unroll
        for (int mt = 0; mt < 4; ++mt)
            #pragma unroll
            for (int nt = 0; nt < 4; ++nt)
                acc[mt][nt] = MFMA16(af[mt], bf[nt], acc[mt][nt], 0, 0, 0);
    }
    #pragma unroll
    for (int mt = 0; mt < 4; ++mt) {
        #pragma unroll
        for (int r = 0; r < 4; ++r) {
            const int j = m0 + wvm * 64 + mt * 16 + lg * 4 + r;
            const float s = qmask[j] / lsum[b * LQ + j];
            float* Hrow = H + ((size_t)(b * LQ + j)) * DD + n0 + wvn * 64;
            #pragma unroll
            for (int nt = 0; nt < 4; ++nt)
                atomicAdd(Hrow + nt * 16 + li, acc[mt][nt][r] * s);
        }
    }
}

// colsum[b,i] = sum_j (qmask[j]/lsum[b,j]) * E[b,j,i]; f16x8 loads, 64-j chunk per block.
__global__ __launch_bounds__(256) void colsum_k(
    const _Float16* __restrict__ E, const float* __restrict__ lsum,
    const float* __restrict__ qmask, float* __restrict__ cs)
{
    __shared__ float ssm[64];
    const int b = blockIdx.y;
    const int j0 = blockIdx.x * 64;
    const int t = threadIdx.x;
    if (t < 64) {
        const int jj = j0 + t;
        ssm[t] = qmask[jj] / lsum[b * LQ + jj];
    }
    __syncthreads();
    const _Float16* Eb = E + ((size_t)(b * LQ + j0)) * LC + t * 8;
    float acc[8] = {};
    #pragma unroll 4
    for (int j = 0; j < 64; ++j) {
        f16x8 v = *(const f16x8*)(Eb + (size_t)j * LC);
        const float s = ssm[j];
        #pragma unroll
        for (int q = 0; q < 8; ++q) acc[q] += s * (float)v[q];
    }
    float* base = cs + b * LC + t * 8;
    #pragma unroll
    for (int q = 0; q < 8; ++q) atomicAdd(base + q, acc[q]);
}

// G[b,i,0:512] = ctx; G[b,i,512:1024] = ctx * colsum
__global__ __launch_bounds__(128) void gwrite(
    const float* __restrict__ ctx, const float* __restrict__ cs, float* __restrict__ G)
{
    const int b = blockIdx.y, i = blockIdx.x, t = threadIdx.x;
    const float c = cs[b * LC + i];
    const size_t ro = (size_t)(b * LC + i);
    const float4 v = *(const float4*)(ctx + ro * DD + t * 4);
    float4 u; u.x = v.x * c; u.y = v.y * c; u.z = v.z * c; u.w = v.w * c;
    *(float4*)(G + ro * (2 * DD) + t * 4) = v;
    *(float4*)(G + ro * (2 * DD) + DD + t * 4) = u;
}

extern "C" void kernel_launch(void* const* d_in, const int* in_sizes, int n_in,
                              void* d_out, int out_size, void* d_ws, size_t ws_size,
                              hipStream_t stream)
{
    (void)in_sizes; (void)n_in; (void)out_size; (void)ws_size;
    const float* ctx = (const float*)d_in[0];
    const float* qry = (const float*)d_in[1];
    const float* w   = (const float*)d_in[2];
    float* G = (float*)d_out;
    float* H = G + (size_t)BB * LC * (2 * DD);

    char* ws = (char*)d_ws;
    _Float16* E  = (_Float16*)ws;                            // 64 MB
    _Float16* cm = (_Float16*)(ws + ((size_t)64 << 20));     // 32 MB
    _Float16* ct = (_Float16*)(ws + ((size_t)96 << 20));     // 32 MB
    _Float16* qh = (_Float16*)(ws + ((size_t)128 << 20));    // 1 MB
    float* stats = (float*)(ws + ((size_t)130 << 20));
    float* cb    = stats;              // BB*LC (written directly, no zero needed)
    float* lsum  = cb + BB * LC;       // BB*LQ  (zeroed)
    float* cs    = lsum + BB * LQ;     // BB*LC  (zeroed)
    float* qb    = cs + BB * LC;       // LQ
    float* qmask = qb + LQ;            // LQ

    zero_k<<<dim3((BB * LQ * DD / 4 + 255) / 256), 256, 0, stream>>>(H, lsum);
    prep_ctx<<<dim3(LC / 64, BB), 256, 0, stream>>>(ctx, w, cm, ct, cb);
    prep_q<<<dim3(LQ), 128, 0, stream>>>(qry, w, qh, qb, qmask);
    gemm1<<<dim3(LQ / 128, LC / 128, BB), 256, 0, stream>>>(qh, cm, cb, qb, E, lsum);
    gemm2<<<dim3(LQ / 128, DD / 128, BB * 4), 256, 0, stream>>>(E, ct, lsum, qmask, H);
    colsum_k<<<dim3(LQ / 64, BB), 256, 0, stream>>>(E, lsum, qmask, cs);
    gwrite<<<dim3(LC, BB), 128, 0, stream>>>(ctx, cs, G);
}